// Round 13
// baseline (156.075 us; speedup 1.0000x reference)
//
#include <hip/hip_runtime.h>

#define NPTS 32768

typedef _Float16 f16;
typedef _Float16 f16x2 __attribute__((ext_vector_type(2)));
typedef _Float16 f16x4 __attribute__((ext_vector_type(4)));
typedef _Float16 f16x8 __attribute__((ext_vector_type(8)));
typedef float f32x2 __attribute__((ext_vector_type(2)));
typedef float f32x4 __attribute__((ext_vector_type(4)));
typedef unsigned int u32x4 __attribute__((ext_vector_type(4)));

union U16 { u32x4 u; f32x4 f; f16x2 h2[4]; f16x4 h4[2]; f16x8 h8; };
union U8h { f16x4 h4; f16x2 h2[2]; };

static __device__ __forceinline__ f16x2 pk_fma(f16x2 a, f16x2 b, f16x2 c) {
  return __builtin_elementwise_fma(a, b, c);
}
static __device__ __forceinline__ f16x2 pk_relu(f16x2 a) {
  f16x2 z = {(f16)0.f, (f16)0.f};
  return __builtin_elementwise_max(a, z);
}
static __device__ __forceinline__ f16x2 pk_cvt(float a, float b) {
  return __builtin_bit_cast(f16x2, __builtin_amdgcn_cvt_pkrtz(a, b));
}

#if __has_builtin(__builtin_amdgcn_mfma_f32_16x16x16f16)
#define HAVE_MFMA16 1
#else
#define HAVE_MFMA16 0
#endif

// used-gas index gi = 0..73 (h2o nets 7,8 unused); g = gi + (gi>=7 ? 2 : 0)
__device__ const unsigned char G_T[74] = {
  0,0,0,0,0,0,0, 0,0,0,0,0,0,0,0,0,0,0,0,0,0,0,0,0,0,0,0,
  1,1,1,1,1,1,1,1,1,1,1,1,1,
  2,2,2,2,2,2,2,2,2,
  3,3,3,
  4,4,4,4,4,4,4,4,4,
  5,5,5,5,5,5,5,5,5,5,5,5,5
};
// channel -> contributing gases (inverse of the scatter tables)
__device__ const unsigned char CH_OFF[30] = {
  0,6,12,18,20,22,24,26,28,30,32,34,36,38,40,42,44,46,49,52,55,58,61,64,
  65,66,68,70,73,76
};
__device__ const unsigned char CH_GAS[76] = {
  0,27,40,49,52,61,  1,28,41,50,53,62,  2,29,42,51,54,63,
  3,55,  4,56,  5,43,  6,44,  3,57,  4,58,  7,45,  8,46,
  9,59,  10,60,  11,47,  12,48,  13,64,  14,65,
  15,30,66,  16,31,67,  17,32,68,  18,33,69,  19,34,70,  20,35,71,
  21,  22,  23,36,  24,37,  25,38,72,  26,39,73
};

// Packed-weight layout in d_ws: uint4 slots, addr = ((gi*22 + slot)*64 + lane).
// 0..7: afrag[mt][ks] (L2 A, 16x16x32) | 8..9: w0h | 10..11: w1h | 12..13: b1h
// 14..17: b2q[mt] | 18..19: A3 Wout^T frags (16x16x16, 2 ks per slot)
// 20..21: wq[mt packed as f32x4 pairs? -> 20..21 hold Wout quads for fallback
#define NSLOT 22

// ---------------------------------------------------------------------------
__global__ __launch_bounds__(64) void k0w_pack(
    const float* __restrict__ W1, const float* __restrict__ b1,
    const float* __restrict__ W2, const float* __restrict__ b2,
    const float* __restrict__ Wout, u32x4* __restrict__ pack)
{
  const int gi   = blockIdx.x;
  const int lane = threadIdx.x;
  const int l15  = lane & 15;
  const int quad = lane >> 4;
  const int g    = gi + (gi >= 7 ? 2 : 0);

  const float* W2g = W2 + g * 4096;
  const float* W1g = W1 + g * 128;
  const float* b1g = b1 + g * 64;
  u32x4* dst = pack + gi * NSLOT * 64 + lane;

  #pragma unroll
  for (int mt = 0; mt < 4; ++mt)
    #pragma unroll
    for (int ks = 0; ks < 2; ++ks) {
      U16 u;
      #pragma unroll
      for (int j = 0; j < 4; ++j) {
        const float* s = W2g + (ks * 32 + quad * 8 + 2 * j) * 64 + mt * 16 + l15;
        u.h2[j] = pk_cvt(s[0], s[64]);
      }
      dst[(mt * 2 + ks) * 64] = u.u;
    }
  #pragma unroll
  for (int ks = 0; ks < 2; ++ks) {
    U16 a, b, c;
    #pragma unroll
    for (int j = 0; j < 4; ++j) {
      int h = ks * 32 + quad * 8 + 2 * j;
      a.h2[j] = pk_cvt(W1g[h],      W1g[h + 1]);
      b.h2[j] = pk_cvt(W1g[64 + h], W1g[64 + h + 1]);
      c.h2[j] = pk_cvt(b1g[h],      b1g[h + 1]);
    }
    dst[(8 + ks) * 64]  = a.u;
    dst[(10 + ks) * 64] = b.u;
    dst[(12 + ks) * 64] = c.u;
  }
  #pragma unroll
  for (int mt = 0; mt < 4; ++mt) {
    U16 u, v;
    u.f = *(const f32x4*)(b2   + g * 64 + mt * 16 + quad * 4);
    v.f = *(const f32x4*)(Wout + g * 64 + mt * 16 + quad * 4);
    dst[(14 + mt) * 64] = u.u;
    dst[(18 + 2 + mt != 0 ? 0 : 0), 0];  // no-op placeholder removed below
    dst[( (mt < 2 ? 20 : 21) ) * 64] = v.u;  // fallback Wout quads (20: mt0.. )
  }
  // correct fallback packing: slots 20,21 hold wq for mt pairs
  {
    U16 v0, v1;
    v0.f = *(const f32x4*)(Wout + g * 64 + 0 * 16 + quad * 4);
    // store per-mt quads individually in slots 20/21 as two halves:
    // slot20 = [mt0, mt1] interleaved f32x2 pairs is awkward — instead we
    // re-store full quads: slot20=mt... (fallback path reloads 14..17-style)
  }
  // A3 fragments for 16x16x16 layer-3 MFMA: lane l15==0 holds
  // Wout[ks*16 + quad*4 + j] as f16, others zero. 2 ks per slot.
  {
    U16 a3a, a3b;
    #pragma unroll
    for (int ks = 0; ks < 4; ++ks) {
      f16x2 lo, hi;
      if (l15 == 0) {
        const float* wsrc = Wout + g * 64 + ks * 16 + quad * 4;
        lo = pk_cvt(wsrc[0], wsrc[1]);
        hi = pk_cvt(wsrc[2], wsrc[3]);
      } else {
        lo = f16x2{(f16)0.f, (f16)0.f};
        hi = lo;
      }
      if (ks < 2) { a3a.h2[ks * 2] = lo; a3a.h2[ks * 2 + 1] = hi; }
      else        { a3b.h2[(ks - 2) * 2] = lo; a3b.h2[(ks - 2) * 2 + 1] = hi; }
    }
    dst[18 * 64] = a3a.u;
    dst[19 * 64] = a3b.u;
  }
}

// ---------------------------------------------------------------------------
// k0: tau_lw / tau_iw only (gases section is fully written by k1 stores).
// ---------------------------------------------------------------------------
__global__ __launch_bounds__(256) void k0_init(
    const float* __restrict__ comp, const float* __restrict__ ke_lw,
    const float* __restrict__ ke_iw, float* __restrict__ out)
{
  const int c = blockIdx.x >> 7;
  const int n = ((blockIdx.x & 127) << 8) + threadIdx.x;
  out[29 * NPTS + c * NPTS + n] = ke_lw[c] * comp[6 * NPTS + n];
  out[58 * NPTS + c * NPTS + n] = ke_iw[c] * comp[7 * NPTS + n];
}

// ---------------------------------------------------------------------------
// k1: CHANNEL-major MLP+reduce. wave = (channel, 128-pt group); loops over
// the channel's 1-6 contributing gases, accumulating tau in registers;
// plain stores (no atomics, no zero-init, no cross-XCD RMW ping-pong).
// Layer-3 = 16x16x16 MFMA: B-frag k=quad*4+j matches acc C-layout rows
// exactly -> relu+cvt feeds acc into MFMA with ZERO shuffles.
// 29 ch x 256 groups = 7424 waves, 1856 blocks.
// ---------------------------------------------------------------------------
__global__ __launch_bounds__(256) void k1_mlp(
    const float* __restrict__ t_p, const float* __restrict__ comp,
    const u32x4* __restrict__ pack, const float* __restrict__ bout,
    float* __restrict__ out)
{
  const int lane = threadIdx.x & 63;
  const int l15  = lane & 15;
  const int quad = lane >> 4;
  const int w    = blockIdx.x * 4 + (threadIdx.x >> 6);
  const int c    = w >> 8;          // channel 0..28
  const int pb   = (w & 255) * 128; // 128 points per wave

  const float2* tp2 = (const float2*)t_p;

  // per-wave t_p fragments (shared across gases): 2 passes x 4 ptiles
  f16x2 x0v[2][4], x1v[2][4];
  #pragma unroll
  for (int ps = 0; ps < 2; ++ps)
    #pragma unroll
    for (int pt = 0; pt < 4; ++pt) {
      float2 xv = tp2[pb + ps * 64 + pt * 16 + l15];
      x0v[ps][pt] = pk_cvt(xv.x, xv.x);
      x1v[ps][pt] = pk_cvt(xv.y, xv.y);
    }

  float acc_tau[2][4];
  #pragma unroll
  for (int ps = 0; ps < 2; ++ps)
    #pragma unroll
    for (int pt = 0; pt < 4; ++pt) acc_tau[ps][pt] = 0.f;

#if !HAVE_MFMA16
  const bool qb0 = (quad & 1) != 0;
  const bool qb1 = (quad & 2) != 0;
#endif

  const int i0 = CH_OFF[c], i1 = CH_OFF[c + 1];
  for (int idx = i0; idx < i1; ++idx) {
    const int gi = CH_GAS[idx];
    const int t  = G_T[gi];
    const int g  = gi + (gi >= 7 ? 2 : 0);

    // ---- load this gas's packed fragments
    const u32x4* pksrc = pack + gi * NSLOT * 64 + lane;
    f16x8 afrag[4][2];
    f32x4 b2q[4];
    #pragma unroll
    for (int mt = 0; mt < 4; ++mt) {
      afrag[mt][0] = __builtin_bit_cast(f16x8, pksrc[(mt * 2 + 0) * 64]);
      afrag[mt][1] = __builtin_bit_cast(f16x8, pksrc[(mt * 2 + 1) * 64]);
      b2q[mt] = __builtin_bit_cast(f32x4, pksrc[(14 + mt) * 64]);
    }
    U16 w0s[2], w1s[2], b1s[2];
    #pragma unroll
    for (int ks = 0; ks < 2; ++ks) {
      w0s[ks].u = pksrc[(8 + ks) * 64];
      w1s[ks].u = pksrc[(10 + ks) * 64];
      b1s[ks].u = pksrc[(12 + ks) * 64];
    }
#if HAVE_MFMA16
    U16 a3a, a3b;
    a3a.u = pksrc[18 * 64];
    a3b.u = pksrc[19 * 64];
    f16x4 a3[4] = { a3a.h4[0], a3a.h4[1], a3b.h4[0], a3b.h4[1] };
#else
    f32x2 wq2[4][2];
    #pragma unroll
    for (int mt = 0; mt < 4; ++mt) {
      // fallback: rebuild Wout quads from A3 slots is impossible; reload
      // from b2q-style packing not present — use global Wout via bout ptr
      // (fallback path unused when MFMA16 exists)
      wq2[mt][0] = f32x2{0.f, 0.f};
      wq2[mt][1] = f32x2{0.f, 0.f};
    }
#endif
    const float bo = bout[g];
    const float* compt = comp + t * NPTS;

    #pragma unroll
    for (int ps = 0; ps < 2; ++ps) {
      // layer 1 -> B fragments (16x16x32: k = ks*32 + quad*8 + j)
      U16 bfrag[2][4];
      #pragma unroll
      for (int ks = 0; ks < 2; ++ks)
        #pragma unroll
        for (int pt = 0; pt < 4; ++pt)
          #pragma unroll
          for (int i = 0; i < 4; ++i)
            bfrag[ks][pt].h2[i] =
                pk_relu(pk_fma(x0v[ps][pt], w0s[ks].h2[i],
                               pk_fma(x1v[ps][pt], w1s[ks].h2[i], b1s[ks].h2[i])));

      #pragma unroll
      for (int pt = 0; pt < 4; ++pt) {
        // layer 2: acc[mt] = W2^T x h1 + b2  (C-layout: col=n=l15, row=quad*4+r)
        f32x4 a4[4];
        #pragma unroll
        for (int mt = 0; mt < 4; ++mt) {
          f32x4 c0 = __builtin_amdgcn_mfma_f32_16x16x32_f16(
              afrag[mt][0], bfrag[0][pt].h8, b2q[mt], 0, 0, 0);
          a4[mt] = __builtin_amdgcn_mfma_f32_16x16x32_f16(
              afrag[mt][1], bfrag[1][pt].h8, c0, 0, 0, 0);
        }

#if HAVE_MFMA16
        // layer 3 via 16x16x16 MFMA: B = relu(h2) cvt'd straight from acc
        f32x4 d3 = { 0.f, 0.f, 0.f, 0.f };
        #pragma unroll
        for (int ks = 0; ks < 4; ++ks) {
          f32x4 z = { 0.f, 0.f, 0.f, 0.f };
          f32x4 r4 = __builtin_elementwise_max(a4[ks], z);
          U8h b3;
          b3.h2[0] = pk_cvt(r4[0], r4[1]);
          b3.h2[1] = pk_cvt(r4[2], r4[3]);
          d3 = __builtin_amdgcn_mfma_f32_16x16x16f16(a3[ks], b3.h4, d3, 0, 0, 0);
        }
        // ke lives in row o=0 => quad 0, reg 0; other lanes hold garbage
        float cvv = compt[pb + ps * 64 + pt * 16 + l15];
        float tau = fmaxf(d3[0] + bo, 0.f) * cvv;
        acc_tau[ps][pt] += tau;
#else
        // fallback: never compiled when MFMA16 exists
        float p = 0.f;
        #pragma unroll
        for (int mt = 0; mt < 4; ++mt)
          #pragma unroll
          for (int r = 0; r < 4; ++r) p += fmaxf(a4[mt][r], 0.f);
        acc_tau[ps][pt] += p;
#endif
      }
    }
  }

  // one owner per (channel, chunk): plain coalesced-ish masked stores
  if (quad == 0) {
    #pragma unroll
    for (int ps = 0; ps < 2; ++ps)
      #pragma unroll
      for (int pt = 0; pt < 4; ++pt)
        out[c * NPTS + pb + ps * 64 + pt * 16 + l15] = acc_tau[ps][pt];
  }
}

// ---------------------------------------------------------------------------
extern "C" void kernel_launch(void* const* d_in, const int* in_sizes, int n_in,
                              void* d_out, int out_size, void* d_ws, size_t ws_size,
                              hipStream_t stream)
{
  const float* t_p   = (const float*)d_in[0];
  const float* comp  = (const float*)d_in[1];
  const float* W1    = (const float*)d_in[2];
  const float* b1    = (const float*)d_in[3];
  const float* W2    = (const float*)d_in[4];
  const float* b2    = (const float*)d_in[5];
  const float* Wout  = (const float*)d_in[6];
  const float* bout  = (const float*)d_in[7];
  const float* ke_lw = (const float*)d_in[8];
  const float* ke_iw = (const float*)d_in[9];
  float* out = (float*)d_out;
  u32x4* pack = (u32x4*)d_ws;   // 74*22*64*16 B = 1.63 MB

  k0w_pack<<<74, 64, 0, stream>>>(W1, b1, W2, b2, Wout, pack);
  k0_init<<<29 * 128, 256, 0, stream>>>(comp, ke_lw, ke_iw, out);
  k1_mlp<<<1856, 256, 0, stream>>>(t_p, comp, pack, bout, out);
}